// Round 5
// baseline (216.252 us; speedup 1.0000x reference)
//
#include <hip/hip_runtime.h>
#include <math.h>

#define B_ROWS 8192
#define C_COLS 4096
#define D_DIM  1024
#define EPSN   1e-12f

typedef float v4f __attribute__((ext_vector_type(4)));
typedef short v8s __attribute__((ext_vector_type(8)));

__device__ __forceinline__ unsigned short bf16_rtn(float x) {
    unsigned int u = __float_as_uint(x);
    u += 0x7fffu + ((u >> 16) & 1u);
    return (unsigned short)(u >> 16);
}

// strict total order (value desc, index asc) == first-occurrence argmax
__device__ __forceinline__ bool better_vi(float v, int i, float V, int I) {
    return (v > V) || (v == V && i < I);
}

// ---------------------------------------------------------------------------
// Kernel 1: wave-per-row normalize + bf16 convert. No LDS, no barriers.
// (byte-identical to the R3-proven version)
// ---------------------------------------------------------------------------
__global__ __launch_bounds__(256) void prep_kernel(
    const float* __restrict__ emb, const float* __restrict__ cen,
    unsigned short* __restrict__ Ah, unsigned short* __restrict__ Bh,
    float* __restrict__ inv_a, float* __restrict__ inv_b)
{
    const int lane = threadIdx.x & 63;
    const int wid  = blockIdx.x * 4 + (threadIdx.x >> 6);
    const float* src; unsigned short* dst; float* invp; int r;
    if (wid < B_ROWS) { src = emb; r = wid;          dst = Ah; invp = inv_a; }
    else              { src = cen; r = wid - B_ROWS; dst = Bh; invp = inv_b; }

    const float* rp = src + (size_t)r * D_DIM;
    float4 v[4];
    float ss = 0.0f;
    #pragma unroll
    for (int j = 0; j < 4; ++j) {
        v[j] = *(const float4*)(rp + (j * 64 + lane) * 4);
        ss += v[j].x * v[j].x + v[j].y * v[j].y + v[j].z * v[j].z + v[j].w * v[j].w;
    }
    #pragma unroll
    for (int off = 1; off < 64; off <<= 1) ss += __shfl_xor(ss, off, 64);

    const float iv = 1.0f / fmaxf(sqrtf(ss), EPSN);
    if (lane == 0) invp[r] = iv;

    unsigned short* dp = dst + (size_t)r * D_DIM;
    #pragma unroll
    for (int j = 0; j < 4; ++j) {
        ushort4 H;
        H.x = bf16_rtn(v[j].x * iv);
        H.y = bf16_rtn(v[j].y * iv);
        H.z = bf16_rtn(v[j].z * iv);
        H.w = bf16_rtn(v[j].w * iv);
        *(ushort4*)(dp + (j * 64 + lane) * 4) = H;
    }
}

// ---------------------------------------------------------------------------
// Kernel 2: single-term bf16 MFMA GEMM + fused per-row top-2 over cols.
// (byte-identical to the R3-proven version; R4's pointer-increment variant
// reverted during the R4-failure bisect)
// ---------------------------------------------------------------------------
__global__ __launch_bounds__(256, 4) void simmax_kernel(
    const unsigned short* __restrict__ Ahg, const unsigned short* __restrict__ Bhg,
    float* __restrict__ p1v, int* __restrict__ p1i,
    float* __restrict__ p2v, int* __restrict__ p2i)
{
    __shared__ unsigned short lds[2 * 4096];  // A | B tiles, 4096 shorts each

    const int tid    = threadIdx.x;
    const int L      = tid & 63;
    const int w      = tid >> 6;
    const int lane15 = L & 15;
    const int quad   = L >> 4;
    const int wr     = w >> 1, wc = w & 1;
    const int row0   = blockIdx.x * 128;
    const int c0     = blockIdx.y * 128;

    // staging: 512 chunks/tile, 2 issues/thread/tile, lane-contiguous LDS dest
    int srow[2], sgq[2];
    #pragma unroll
    for (int i = 0; i < 2; ++i) {
        int p   = i * 256 + tid;
        int rr  = p >> 2;
        srow[i] = rr;
        sgq[i]  = (p & 3) ^ ((rr >> 1) & 3);
    }
    size_t oA[2], oB[2];
    #pragma unroll
    for (int i = 0; i < 2; ++i) {
        oA[i] = (size_t)(row0 + srow[i]) * D_DIM + sgq[i] * 8;
        oB[i] = (size_t)(c0   + srow[i]) * D_DIM + sgq[i] * 8;
    }
    const int lb[2] = { (0 * 256 + w * 64) * 8, (1 * 256 + w * 64) * 8 };  // shorts

    v4f acc[4][4];
    #pragma unroll
    for (int mt = 0; mt < 4; ++mt)
        #pragma unroll
        for (int nt = 0; nt < 4; ++nt) acc[mt][nt] = (v4f)0.0f;

    int fA[4], fB[4];
    #pragma unroll
    for (int t = 0; t < 4; ++t) {
        int rA = wr * 64 + t * 16 + lane15;
        fA[t] = (rA * 4 + (quad ^ ((rA >> 1) & 3))) * 8;
        int rB = wc * 64 + t * 16 + lane15;
        fB[t] = (rB * 4 + (quad ^ ((rB >> 1) & 3))) * 8;
    }

    for (int kc = 0; kc < D_DIM / 32; ++kc) {
        const int kb = kc * 32;
        #pragma unroll
        for (int i = 0; i < 2; ++i) {
            __builtin_amdgcn_global_load_lds(
                (const __attribute__((address_space(1))) void*)(Ahg + oA[i] + kb),
                (__attribute__((address_space(3))) void*)&lds[0 + lb[i]], 16, 0, 0);
            __builtin_amdgcn_global_load_lds(
                (const __attribute__((address_space(1))) void*)(Bhg + oB[i] + kb),
                (__attribute__((address_space(3))) void*)&lds[4096 + lb[i]], 16, 0, 0);
        }
        __syncthreads();

        v8s fah[4], fbh[4];
        #pragma unroll
        for (int t = 0; t < 4; ++t) {
            fah[t] = *(const v8s*)&lds[0    + fA[t]];
            fbh[t] = *(const v8s*)&lds[4096 + fB[t]];
        }
        #pragma unroll
        for (int mt = 0; mt < 4; ++mt)
            #pragma unroll
            for (int nt = 0; nt < 4; ++nt)
                acc[mt][nt] = __builtin_amdgcn_mfma_f32_16x16x32_bf16(fah[mt], fbh[nt], acc[mt][nt], 0, 0, 0);
        __syncthreads();
    }

    // fused top-2 epilogue. C/D layout: col = lane&15, row = quad*4 + reg.
    const int pc = blockIdx.y * 2 + wc;  // 0..63 column chunk id
    #pragma unroll
    for (int mt = 0; mt < 4; ++mt) {
        #pragma unroll
        for (int r = 0; r < 4; ++r) {
            float a1v = acc[mt][0][r];
            int   a1i = c0 + wc * 64 + 0 * 16 + lane15;
            float a2v = -1e30f;
            int   a2i = 0x7fffffff;
            #pragma unroll
            for (int nt = 1; nt < 4; ++nt) {
                float v  = acc[mt][nt][r];
                int   ci = c0 + wc * 64 + nt * 16 + lane15;
                if (better_vi(v, ci, a1v, a1i))      { a2v = a1v; a2i = a1i; a1v = v; a1i = ci; }
                else if (better_vi(v, ci, a2v, a2i)) { a2v = v;   a2i = ci; }
            }
            #pragma unroll
            for (int off = 8; off; off >>= 1) {
                float b1v = __shfl_down(a1v, off, 64); int b1i = __shfl_down(a1i, off, 64);
                float b2v = __shfl_down(a2v, off, 64); int b2i = __shfl_down(a2i, off, 64);
                if (better_vi(b1v, b1i, a1v, a1i)) {
                    if (better_vi(a1v, a1i, b2v, b2i)) { a2v = a1v; a2i = a1i; }
                    else                               { a2v = b2v; a2i = b2i; }
                    a1v = b1v; a1i = b1i;
                } else if (better_vi(b1v, b1i, a2v, a2i)) {
                    a2v = b1v; a2i = b1i;
                }
            }
            if (lane15 == 0) {
                int rg = row0 + wr * 64 + mt * 16 + quad * 4 + r;
                size_t ix = (size_t)rg * 64 + pc;  // [row][chunk] layout
                p1v[ix] = a1v; p1i[ix] = a1i;
                p2v[ix] = a2v; p2i[ix] = a2i;
            }
        }
    }
}

// ---------------------------------------------------------------------------
// Kernel 3: R3-proven structure (wave per row, 4 rows/block, no new sync).
// ONLY change vs R3: the 4-candidate rescore loop is reordered j-outer so the
// 4 gather streams issue back-to-back (4-way memory-level parallelism instead
// of 4 serial dependent dot products). Per-candidate fp32 summation order is
// unchanged -> bit-identical results to R3.
// ---------------------------------------------------------------------------
__global__ __launch_bounds__(256) void finalize_kernel(
    const float* __restrict__ emb, const float* __restrict__ cen,
    const float* __restrict__ inv_a, const float* __restrict__ inv_b,
    const float* __restrict__ p1v, const int* __restrict__ p1i,
    const float* __restrict__ p2v, const int* __restrict__ p2i,
    float* __restrict__ out)
{
    const int lane = threadIdx.x & 63;
    const int row  = blockIdx.x * 4 + (threadIdx.x >> 6);
    const size_t base = (size_t)row * 64 + lane;

    // per-lane sorted-4 list (2 real + 2 sentinels)
    float v[4]; int ix[4];
    v[0] = p1v[base]; ix[0] = p1i[base];
    v[1] = p2v[base]; ix[1] = p2i[base];
    v[2] = -1e30f;    ix[2] = 0x7ffffffe;
    v[3] = -1e30f;    ix[3] = 0x7fffffff;

    // butterfly: each step merges disjoint candidate sets; all lanes converge
    #pragma unroll
    for (int off = 1; off < 64; off <<= 1) {
        float ov[4]; int oi[4];
        #pragma unroll
        for (int k = 0; k < 4; ++k) {
            ov[k] = __shfl_xor(v[k],  off, 64);
            oi[k] = __shfl_xor(ix[k], off, 64);
        }
        #pragma unroll
        for (int k = 0; k < 4; ++k) {
            float bv = ov[k]; int bi = oi[k];
            bool b0 = better_vi(bv, bi, v[0], ix[0]);
            bool b1 = better_vi(bv, bi, v[1], ix[1]);
            bool b2 = better_vi(bv, bi, v[2], ix[2]);
            bool b3 = better_vi(bv, bi, v[3], ix[3]);
            float nv3 = b2 ? v[2] : (b3 ? bv : v[3]); int ni3 = b2 ? ix[2] : (b3 ? bi : ix[3]);
            float nv2 = b1 ? v[1] : (b2 ? bv : v[2]); int ni2 = b1 ? ix[1] : (b2 ? bi : ix[2]);
            float nv1 = b0 ? v[0] : (b1 ? bv : v[1]); int ni1 = b0 ? ix[0] : (b1 ? bi : ix[1]);
            float nv0 = b0 ? bv   : v[0];             int ni0 = b0 ? bi    : ix[0];
            v[0] = nv0; ix[0] = ni0; v[1] = nv1; ix[1] = ni1;
            v[2] = nv2; ix[2] = ni2; v[3] = nv3; ix[3] = ni3;
        }
    }
    // 128 real distinct candidates per row => all 4 slots real & distinct

    // exact fp32 rescore of the 4 candidates, j-outer for 4-way MLP
    const float* er = emb + (size_t)row * D_DIM;
    const float* cr0 = cen + (size_t)ix[0] * D_DIM;
    const float* cr1 = cen + (size_t)ix[1] * D_DIM;
    const float* cr2 = cen + (size_t)ix[2] * D_DIM;
    const float* cr3 = cen + (size_t)ix[3] * D_DIM;

    float d[4] = { 0.0f, 0.0f, 0.0f, 0.0f };
    #pragma unroll
    for (int j = 0; j < 4; ++j) {
        int e = (j * 64 + lane) * 4;
        float4 ev = *(const float4*)(er  + e);
        float4 c0 = *(const float4*)(cr0 + e);
        float4 c1 = *(const float4*)(cr1 + e);
        float4 c2 = *(const float4*)(cr2 + e);
        float4 c3 = *(const float4*)(cr3 + e);
        d[0] += ev.x * c0.x + ev.y * c0.y + ev.z * c0.z + ev.w * c0.w;
        d[1] += ev.x * c1.x + ev.y * c1.y + ev.z * c1.z + ev.w * c1.w;
        d[2] += ev.x * c2.x + ev.y * c2.y + ev.z * c2.z + ev.w * c2.w;
        d[3] += ev.x * c3.x + ev.y * c3.y + ev.z * c3.z + ev.w * c3.w;
    }
    #pragma unroll
    for (int off = 1; off < 64; off <<= 1) {
        #pragma unroll
        for (int c = 0; c < 4; ++c) d[c] += __shfl_xor(d[c], off, 64);
    }

    if (lane == 0) {
        const float ia = inv_a[row];
        float m = -1e30f; int ci = 0x7fffffff;
        #pragma unroll
        for (int c = 0; c < 4; ++c) {
            float s = d[c] * ia * inv_b[ix[c]];
            if (better_vi(s, ix[c], m, ci)) { m = s; ci = ix[c]; }
        }
        if (m <= 0.0f) ci = 0;  // all sims clip to 0 -> argmax = 0
        float ms = fminf(fmaxf(m, 0.0f), 1.0f);
        out[row]          = fminf(fmaxf(sqrtf(1.0f - ms), 0.0f), 1.0f);
        out[B_ROWS + row] = (float)ci;
    }
}

// ---------------------------------------------------------------------------
// Workspace (~33 MB): Ah 16MB | Bh 8MB | inv_a 32KB | inv_b 16KB |
//                     p1v/p1i/p2v/p2i 2MB each ([row][chunk] layout)
// ---------------------------------------------------------------------------
extern "C" void kernel_launch(void* const* d_in, const int* in_sizes, int n_in,
                              void* d_out, int out_size, void* d_ws, size_t ws_size,
                              hipStream_t stream)
{
    const float* emb = (const float*)d_in[0];
    const float* cen = (const float*)d_in[1];
    float* out = (float*)d_out;

    unsigned short* Ahp = (unsigned short*)d_ws;
    unsigned short* Bhp = Ahp + (size_t)B_ROWS * D_DIM;
    float* inv_a = (float*)(Bhp + (size_t)C_COLS * D_DIM);
    float* inv_b = inv_a + B_ROWS;
    float* p1v   = inv_b + C_COLS;
    int*   p1i   = (int*)(p1v + (size_t)64 * B_ROWS);
    float* p2v   = (float*)(p1i + (size_t)64 * B_ROWS);
    int*   p2i   = (int*)(p2v + (size_t)64 * B_ROWS);

    prep_kernel<<<(B_ROWS + C_COLS) / 4, 256, 0, stream>>>(emb, cen, Ahp, Bhp, inv_a, inv_b);

    dim3 grid(B_ROWS / 128, C_COLS / 128);
    simmax_kernel<<<grid, 256, 0, stream>>>(Ahp, Bhp, p1v, p1i, p2v, p2i);

    finalize_kernel<<<B_ROWS / 4, 256, 0, stream>>>(emb, cen, inv_a, inv_b,
                                                    p1v, p1i, p2v, p2i, out);
}

// Round 6
// 203.205 us; speedup vs baseline: 1.0642x; 1.0642x over previous
//
#include <hip/hip_runtime.h>
#include <math.h>

#define B_ROWS 8192
#define C_COLS 4096
#define D_DIM  1024
#define EPSN   1e-12f

typedef float v4f __attribute__((ext_vector_type(4)));
typedef short v8s __attribute__((ext_vector_type(8)));

__device__ __forceinline__ unsigned short bf16_rtn(float x) {
    unsigned int u = __float_as_uint(x);
    u += 0x7fffu + ((u >> 16) & 1u);
    return (unsigned short)(u >> 16);
}

// strict total order (value desc, index asc) == first-occurrence argmax
__device__ __forceinline__ bool better_vi(float v, int i, float V, int I) {
    return (v > V) || (v == V && i < I);
}

// ---------------------------------------------------------------------------
// Kernel 1: wave-per-row normalize + bf16 convert. (R3-proven, unchanged)
// ---------------------------------------------------------------------------
__global__ __launch_bounds__(256) void prep_kernel(
    const float* __restrict__ emb, const float* __restrict__ cen,
    unsigned short* __restrict__ Ah, unsigned short* __restrict__ Bh,
    float* __restrict__ inv_a, float* __restrict__ inv_b)
{
    const int lane = threadIdx.x & 63;
    const int wid  = blockIdx.x * 4 + (threadIdx.x >> 6);
    const float* src; unsigned short* dst; float* invp; int r;
    if (wid < B_ROWS) { src = emb; r = wid;          dst = Ah; invp = inv_a; }
    else              { src = cen; r = wid - B_ROWS; dst = Bh; invp = inv_b; }

    const float* rp = src + (size_t)r * D_DIM;
    float4 v[4];
    float ss = 0.0f;
    #pragma unroll
    for (int j = 0; j < 4; ++j) {
        v[j] = *(const float4*)(rp + (j * 64 + lane) * 4);
        ss += v[j].x * v[j].x + v[j].y * v[j].y + v[j].z * v[j].z + v[j].w * v[j].w;
    }
    #pragma unroll
    for (int off = 1; off < 64; off <<= 1) ss += __shfl_xor(ss, off, 64);

    const float iv = 1.0f / fmaxf(sqrtf(ss), EPSN);
    if (lane == 0) invp[r] = iv;

    unsigned short* dp = dst + (size_t)r * D_DIM;
    #pragma unroll
    for (int j = 0; j < 4; ++j) {
        ushort4 H;
        H.x = bf16_rtn(v[j].x * iv);
        H.y = bf16_rtn(v[j].y * iv);
        H.z = bf16_rtn(v[j].z * iv);
        H.w = bf16_rtn(v[j].w * iv);
        *(ushort4*)(dp + (j * 64 + lane) * 4) = H;
    }
}

// ---------------------------------------------------------------------------
// Kernel 2: single-term bf16 MFMA GEMM + fused per-row top-2 over cols.
// R6 change: BK=64 (was 32) -- halves the barrier-pair count (16 iters), 32
// MFMA per wave per barrier window, 32 KB LDS (still 4 blocks/CU by LDS).
// XOR-swizzle: logical granule q of row r lives at phys chunk r*8 + (q^(r&7)).
// Row stride is now 128 B (= full bank wrap) so frag reads / staging writes
// are 2-way aliased -- free per m136. Staging collapses to 2 base pointers:
// the swizzled column (tid&7)^((tid>>3)&7) is identical for all 4 issues
// (i*256 preserves both tid&7 and (tid>>3)&7), and rA&7 == lane15&7 for all
// fragment tiles. Numerically identical accumulation order to R5.
// ---------------------------------------------------------------------------
__global__ __launch_bounds__(256, 4) void simmax_kernel(
    const unsigned short* __restrict__ Ahg, const unsigned short* __restrict__ Bhg,
    float* __restrict__ p1v, int* __restrict__ p1i,
    float* __restrict__ p2v, int* __restrict__ p2i)
{
    __shared__ unsigned short lds[2 * 8192];  // A | B tiles, 128 rows x 64 bf16

    const int tid    = threadIdx.x;
    const int L      = tid & 63;
    const int w      = tid >> 6;
    const int lane15 = L & 15;
    const int quad   = L >> 4;
    const int wr     = w >> 1, wc = w & 1;
    const int row0   = blockIdx.x * 128;
    const int c0     = blockIdx.y * 128;

    // staging: 1024 chunks/tile, 4 issues/thread/tile.
    // issue i covers rows i*32 + (tid>>3), swizzled col constant across i.
    const int scol = (tid & 7) ^ ((tid >> 3) & 7);
    const unsigned short* aBase = Ahg + (size_t)(row0 + (tid >> 3)) * D_DIM + scol * 8;
    const unsigned short* bBase = Bhg + (size_t)(c0   + (tid >> 3)) * D_DIM + scol * 8;

    v4f acc[4][4];
    #pragma unroll
    for (int mt = 0; mt < 4; ++mt)
        #pragma unroll
        for (int nt = 0; nt < 4; ++nt) acc[mt][nt] = (v4f)0.0f;

    // fragment geometry: row base offsets (shorts) + per-half swizzled col
    int rAo[4], rBo[4];
    #pragma unroll
    for (int t = 0; t < 4; ++t) {
        rAo[t] = (wr * 64 + t * 16 + lane15) * 64;  // row * 8 chunks * 8 shorts
        rBo[t] = (wc * 64 + t * 16 + lane15) * 64;
    }
    const int s7 = lane15 & 7;
    const int cq[2] = { (quad ^ s7) * 8, ((4 + quad) ^ s7) * 8 };  // shorts

    for (int kc = 0; kc < D_DIM / 64; ++kc) {
        const int kb = kc * 64;
        #pragma unroll
        for (int i = 0; i < 4; ++i) {
            __builtin_amdgcn_global_load_lds(
                (const __attribute__((address_space(1))) void*)(aBase + (size_t)i * 32 * D_DIM + kb),
                (__attribute__((address_space(3))) void*)&lds[(i * 256 + w * 64) * 8], 16, 0, 0);
            __builtin_amdgcn_global_load_lds(
                (const __attribute__((address_space(1))) void*)(bBase + (size_t)i * 32 * D_DIM + kb),
                (__attribute__((address_space(3))) void*)&lds[8192 + (i * 256 + w * 64) * 8], 16, 0, 0);
        }
        __syncthreads();

        #pragma unroll
        for (int h = 0; h < 2; ++h) {
            v8s fah[4], fbh[4];
            #pragma unroll
            for (int t = 0; t < 4; ++t) {
                fah[t] = *(const v8s*)&lds[rAo[t] + cq[h]];
                fbh[t] = *(const v8s*)&lds[8192 + rBo[t] + cq[h]];
            }
            #pragma unroll
            for (int mt = 0; mt < 4; ++mt)
                #pragma unroll
                for (int nt = 0; nt < 4; ++nt)
                    acc[mt][nt] = __builtin_amdgcn_mfma_f32_16x16x32_bf16(fah[mt], fbh[nt], acc[mt][nt], 0, 0, 0);
        }
        __syncthreads();
    }

    // fused top-2 epilogue. C/D layout: col = lane&15, row = quad*4 + reg.
    const int pc = blockIdx.y * 2 + wc;  // 0..63 column chunk id
    #pragma unroll
    for (int mt = 0; mt < 4; ++mt) {
        #pragma unroll
        for (int r = 0; r < 4; ++r) {
            float a1v = acc[mt][0][r];
            int   a1i = c0 + wc * 64 + 0 * 16 + lane15;
            float a2v = -1e30f;
            int   a2i = 0x7fffffff;
            #pragma unroll
            for (int nt = 1; nt < 4; ++nt) {
                float v  = acc[mt][nt][r];
                int   ci = c0 + wc * 64 + nt * 16 + lane15;
                if (better_vi(v, ci, a1v, a1i))      { a2v = a1v; a2i = a1i; a1v = v; a1i = ci; }
                else if (better_vi(v, ci, a2v, a2i)) { a2v = v;   a2i = ci; }
            }
            #pragma unroll
            for (int off = 8; off; off >>= 1) {
                float b1v = __shfl_down(a1v, off, 64); int b1i = __shfl_down(a1i, off, 64);
                float b2v = __shfl_down(a2v, off, 64); int b2i = __shfl_down(a2i, off, 64);
                if (better_vi(b1v, b1i, a1v, a1i)) {
                    if (better_vi(a1v, a1i, b2v, b2i)) { a2v = a1v; a2i = a1i; }
                    else                               { a2v = b2v; a2i = b2i; }
                    a1v = b1v; a1i = b1i;
                } else if (better_vi(b1v, b1i, a2v, a2i)) {
                    a2v = b1v; a2i = b1i;
                }
            }
            if (lane15 == 0) {
                int rg = row0 + wr * 64 + mt * 16 + quad * 4 + r;
                size_t ix = (size_t)rg * 64 + pc;  // [row][chunk] layout
                p1v[ix] = a1v; p1i[ix] = a1i;
                p2v[ix] = a2v; p2i[ix] = a2i;
            }
        }
    }
}

// ---------------------------------------------------------------------------
// Kernel 3: R3/R5-proven finalize (wave per row, 4 rows/block, j-outer MLP
// rescore). Unchanged.
// ---------------------------------------------------------------------------
__global__ __launch_bounds__(256) void finalize_kernel(
    const float* __restrict__ emb, const float* __restrict__ cen,
    const float* __restrict__ inv_a, const float* __restrict__ inv_b,
    const float* __restrict__ p1v, const int* __restrict__ p1i,
    const float* __restrict__ p2v, const int* __restrict__ p2i,
    float* __restrict__ out)
{
    const int lane = threadIdx.x & 63;
    const int row  = blockIdx.x * 4 + (threadIdx.x >> 6);
    const size_t base = (size_t)row * 64 + lane;

    float v[4]; int ix[4];
    v[0] = p1v[base]; ix[0] = p1i[base];
    v[1] = p2v[base]; ix[1] = p2i[base];
    v[2] = -1e30f;    ix[2] = 0x7ffffffe;
    v[3] = -1e30f;    ix[3] = 0x7fffffff;

    #pragma unroll
    for (int off = 1; off < 64; off <<= 1) {
        float ov[4]; int oi[4];
        #pragma unroll
        for (int k = 0; k < 4; ++k) {
            ov[k] = __shfl_xor(v[k],  off, 64);
            oi[k] = __shfl_xor(ix[k], off, 64);
        }
        #pragma unroll
        for (int k = 0; k < 4; ++k) {
            float bv = ov[k]; int bi = oi[k];
            bool b0 = better_vi(bv, bi, v[0], ix[0]);
            bool b1 = better_vi(bv, bi, v[1], ix[1]);
            bool b2 = better_vi(bv, bi, v[2], ix[2]);
            bool b3 = better_vi(bv, bi, v[3], ix[3]);
            float nv3 = b2 ? v[2] : (b3 ? bv : v[3]); int ni3 = b2 ? ix[2] : (b3 ? bi : ix[3]);
            float nv2 = b1 ? v[1] : (b2 ? bv : v[2]); int ni2 = b1 ? ix[1] : (b2 ? bi : ix[2]);
            float nv1 = b0 ? v[0] : (b1 ? bv : v[1]); int ni1 = b0 ? ix[0] : (b1 ? bi : ix[1]);
            float nv0 = b0 ? bv   : v[0];             int ni0 = b0 ? bi    : ix[0];
            v[0] = nv0; ix[0] = ni0; v[1] = nv1; ix[1] = ni1;
            v[2] = nv2; ix[2] = ni2; v[3] = nv3; ix[3] = ni3;
        }
    }

    const float* er = emb + (size_t)row * D_DIM;
    const float* cr0 = cen + (size_t)ix[0] * D_DIM;
    const float* cr1 = cen + (size_t)ix[1] * D_DIM;
    const float* cr2 = cen + (size_t)ix[2] * D_DIM;
    const float* cr3 = cen + (size_t)ix[3] * D_DIM;

    float d[4] = { 0.0f, 0.0f, 0.0f, 0.0f };
    #pragma unroll
    for (int j = 0; j < 4; ++j) {
        int e = (j * 64 + lane) * 4;
        float4 ev = *(const float4*)(er  + e);
        float4 c0 = *(const float4*)(cr0 + e);
        float4 c1 = *(const float4*)(cr1 + e);
        float4 c2 = *(const float4*)(cr2 + e);
        float4 c3 = *(const float4*)(cr3 + e);
        d[0] += ev.x * c0.x + ev.y * c0.y + ev.z * c0.z + ev.w * c0.w;
        d[1] += ev.x * c1.x + ev.y * c1.y + ev.z * c1.z + ev.w * c1.w;
        d[2] += ev.x * c2.x + ev.y * c2.y + ev.z * c2.z + ev.w * c2.w;
        d[3] += ev.x * c3.x + ev.y * c3.y + ev.z * c3.z + ev.w * c3.w;
    }
    #pragma unroll
    for (int off = 1; off < 64; off <<= 1) {
        #pragma unroll
        for (int c = 0; c < 4; ++c) d[c] += __shfl_xor(d[c], off, 64);
    }

    if (lane == 0) {
        const float ia = inv_a[row];
        float m = -1e30f; int ci = 0x7fffffff;
        #pragma unroll
        for (int c = 0; c < 4; ++c) {
            float s = d[c] * ia * inv_b[ix[c]];
            if (better_vi(s, ix[c], m, ci)) { m = s; ci = ix[c]; }
        }
        if (m <= 0.0f) ci = 0;  // all sims clip to 0 -> argmax = 0
        float ms = fminf(fmaxf(m, 0.0f), 1.0f);
        out[row]          = fminf(fmaxf(sqrtf(1.0f - ms), 0.0f), 1.0f);
        out[B_ROWS + row] = (float)ci;
    }
}

// ---------------------------------------------------------------------------
// Workspace (~33 MB): Ah 16MB | Bh 8MB | inv_a 32KB | inv_b 16KB |
//                     p1v/p1i/p2v/p2i 2MB each ([row][chunk] layout)
// ---------------------------------------------------------------------------
extern "C" void kernel_launch(void* const* d_in, const int* in_sizes, int n_in,
                              void* d_out, int out_size, void* d_ws, size_t ws_size,
                              hipStream_t stream)
{
    const float* emb = (const float*)d_in[0];
    const float* cen = (const float*)d_in[1];
    float* out = (float*)d_out;

    unsigned short* Ahp = (unsigned short*)d_ws;
    unsigned short* Bhp = Ahp + (size_t)B_ROWS * D_DIM;
    float* inv_a = (float*)(Bhp + (size_t)C_COLS * D_DIM);
    float* inv_b = inv_a + B_ROWS;
    float* p1v   = inv_b + C_COLS;
    int*   p1i   = (int*)(p1v + (size_t)64 * B_ROWS);
    float* p2v   = (float*)(p1i + (size_t)64 * B_ROWS);
    int*   p2i   = (int*)(p2v + (size_t)64 * B_ROWS);

    prep_kernel<<<(B_ROWS + C_COLS) / 4, 256, 0, stream>>>(emb, cen, Ahp, Bhp, inv_a, inv_b);

    dim3 grid(B_ROWS / 128, C_COLS / 128);
    simmax_kernel<<<grid, 256, 0, stream>>>(Ahp, Bhp, p1v, p1i, p2v, p2i);

    finalize_kernel<<<B_ROWS / 4, 256, 0, stream>>>(emb, cen, inv_a, inv_b,
                                                    p1v, p1i, p2v, p2i, out);
}